// Round 7
// baseline (30.136 us; speedup 1.0000x reference)
//
#include <hip/hip_runtime.h>

#define GDIM 7
#define CELLS 49          // 7*7
#define CH 30
#define FPB (CH * CELLS)  // 1470 floats per batch
#define BLK 256
#define NGROUPS 64
#define GSTRIDE 16        // u64s per group slot (128 B line stride)
#define CNT_BITS 11
#define CNT_MASK ((1ull << CNT_BITS) - 1ull)
#define FIX_SCALE 16777216.0  // 2^24 fixed-point

__device__ __forceinline__ float iou_fn(float ax1, float ay1, float ax2, float ay2,
                                        float bx1, float by1, float bx2, float by2) {
    float ix1 = fmaxf(ax1, bx1);
    float iy1 = fmaxf(ay1, by1);
    float ix2 = fminf(ax2, bx2);
    float iy2 = fminf(ay2, by2);
    float iw = fmaxf(ix2 - ix1, 0.0f);
    float ih = fmaxf(iy2 - iy1, 0.0f);
    float inter = iw * ih;
    float aa = (ax2 - ax1) * (ay2 - ay1);
    float ab = (bx2 - bx1) * (by2 - by1);
    return inter > 0.0f ? inter / (aa + ab - inter) : 0.0f;
}

__global__ __launch_bounds__(BLK) void yolo_onepass(const float* __restrict__ pred,
                                                    const float* __restrict__ lab,
                                                    unsigned long long* __restrict__ gacc,
                                                    unsigned long long* __restrict__ racc,
                                                    float* __restrict__ out,
                                                    int nblocks, float inv_b) {
    const int tid = threadIdx.x;
    const int i = blockIdx.x * BLK + tid;   // grid sized exactly; no guard

    const int b = i / CELLS;
    const int cell = i - b * CELLS;
    const int mr = cell / GDIM;      // first spatial index -> m (added to cx)
    const int nc = cell - mr * GDIM; // second spatial index -> n (added to cy)
    const float* p = pred + (size_t)b * FPB + cell;
    const float* l = lab  + (size_t)b * FPB + cell;

    float pv[10], lv[10];
    #pragma unroll
    for (int c = 0; c < 10; ++c) pv[c] = p[c * CELLS];
    #pragma unroll
    for (int c = 0; c < 10; ++c) lv[c] = l[c * CELLS];

    float cls = 0.0f;
    #pragma unroll
    for (int c = 10; c < CH; ++c) {
        float d = p[c * CELLS] - l[c * CELLS];
        cls = fmaf(d, d, cls);
    }

    const float fm = (float)mr, fn = (float)nc;

    float gcx = (lv[0] + fm) / 7.0f;
    float gcy = (lv[1] + fn) / 7.0f;
    float gx1 = gcx - lv[2] * 0.5f, gy1 = gcy - lv[3] * 0.5f;
    float gx2 = gcx + lv[2] * 0.5f, gy2 = gcy + lv[3] * 0.5f;

    float c1x = (pv[0] + fm) / 7.0f;
    float c1y = (pv[1] + fn) / 7.0f;
    float b1x1 = c1x - pv[2] * 0.5f, b1y1 = c1y - pv[3] * 0.5f;
    float b1x2 = c1x + pv[2] * 0.5f, b1y2 = c1y + pv[3] * 0.5f;

    float c2x = (pv[5] + fm) / 7.0f;
    float c2y = (pv[6] + fn) / 7.0f;
    float b2x1 = c2x - pv[7] * 0.5f, b2y1 = c2y - pv[8] * 0.5f;
    float b2x2 = c2x + pv[7] * 0.5f, b2y2 = c2y + pv[8] * 0.5f;

    float iou1 = iou_fn(b1x1, b1y1, b1x2, b1y2, gx1, gy1, gx2, gy2);
    float iou2 = iou_fn(b2x1, b2y1, b2x2, b2y2, gx1, gy1, gx2, gy2);
    bool use1 = iou1 >= iou2;

    float d0 = pv[0] - lv[0], d1 = pv[1] - lv[1];
    float s2 = sqrtf(pv[2]) - sqrtf(lv[2]);
    float s3 = sqrtf(pv[3]) - sqrtf(lv[3]);
    float coor1 = d0 * d0 + d1 * d1 + s2 * s2 + s3 * s3;

    float d5 = pv[5] - lv[5], d6 = pv[6] - lv[6];
    float s7 = sqrtf(pv[7]) - sqrtf(lv[7]);
    float s8 = sqrtf(pv[8]) - sqrtf(lv[8]);
    float coor2 = d5 * d5 + d6 * d6 + s7 * s7 + s8 * s8;

    float coor = 5.0f * (use1 ? coor1 : coor2);

    float e1 = pv[4] - iou1; e1 *= e1;
    float e2 = pv[9] - iou2; e2 *= e2;
    float obj_conf   = use1 ? e1 : e2;
    float noobj_obj  = 0.5f * (use1 ? e2 : e1);
    float noobj_none = 0.5f * (pv[4] * pv[4] + pv[9] * pv[9]);

    bool obj = (lv[4] == 1.0f);
    float per_cell = obj ? (coor + obj_conf + noobj_obj + cls) : noobj_none;

    // ---- block reduction (deterministic within block) ----
    float v = per_cell;
    #pragma unroll
    for (int off = 32; off > 0; off >>= 1) v += __shfl_down(v, off, 64);

    __shared__ float swave[BLK / 64];
    const int lane = tid & 63;
    const int wid = tid >> 6;
    if (lane == 0) swave[wid] = v;
    __syncthreads();
    if (tid == 0) {
        float s = 0.0f;
        #pragma unroll
        for (int w = 0; w < BLK / 64; ++w) s += swave[w];

        // ---- hierarchical packed-atomic tree (exact -> deterministic) ----
        // Level 1: 64 group lines (128 B apart), <=25 RMWs each, in parallel.
        // Value rides inside the atomic -> no fence, no memory re-read.
        const int g = blockIdx.x & (NGROUPS - 1);
        const int remainder = nblocks & (NGROUPS - 1);           // 1568%64 = 32
        const int gsize = (nblocks >> 6) + (g < remainder ? 1 : 0); // 25 or 24

        unsigned long long fixed =
            (unsigned long long)((double)s * FIX_SCALE + 0.5);
        unsigned long long contrib = (fixed << CNT_BITS) | 1ull;
        unsigned long long prev = atomicAdd(&gacc[g * GSTRIDE], contrib);

        if ((prev & CNT_MASK) == (unsigned long long)(gsize - 1)) {
            // Group complete: forward group total to the root line.
            unsigned long long gtotal = (prev + contrib) >> CNT_BITS;
            unsigned long long rcontrib = (gtotal << CNT_BITS) | 1ull;
            unsigned long long rprev = atomicAdd(racc, rcontrib);
            if ((rprev & CNT_MASK) == (unsigned long long)(NGROUPS - 1)) {
                unsigned long long total = (rprev + rcontrib) >> CNT_BITS;
                out[0] = (float)((double)total * (1.0 / FIX_SCALE) * (double)inv_b);
            }
        }
    }
}

extern "C" void kernel_launch(void* const* d_in, const int* in_sizes, int n_in,
                              void* d_out, int out_size, void* d_ws, size_t ws_size,
                              hipStream_t stream) {
    const float* pred = (const float*)d_in[0];
    const float* lab  = (const float*)d_in[1];
    int B = in_sizes[0] / FPB;                    // 8192
    int total_cells = B * CELLS;                  // 401408 = 1568 * 256 exactly
    int nblocks = total_cells / BLK;              // 1568

    unsigned long long* gacc = (unsigned long long*)d_ws;               // 64 slots, 128 B stride
    unsigned long long* racc = gacc + NGROUPS * GSTRIDE;                // root line
    float* out = (float*)d_out;

    // zero group + root accumulators (one tiny in-graph memset)
    hipMemsetAsync(gacc, 0, (NGROUPS * GSTRIDE + 1) * sizeof(unsigned long long), stream);
    yolo_onepass<<<nblocks, BLK, 0, stream>>>(pred, lab, gacc, racc, out,
                                              nblocks, 1.0f / (float)B);
}

// Round 8
// 26.158 us; speedup vs baseline: 1.1521x; 1.1521x over previous
//
#include <hip/hip_runtime.h>

#define GDIM 7
#define CELLS 49            // 7*7
#define CH 30
#define FPB (CH * CELLS)    // 1470 floats per batch
#define BPB 2               // batches per block: 2*1470*4B = 11760 B, 16B-aligned
#define BLK 256
#define NF4 ((BPB * FPB) / 4)   // 735 float4 per array

__device__ __forceinline__ float iou_fn(float ax1, float ay1, float ax2, float ay2,
                                        float bx1, float by1, float bx2, float by2) {
    float ix1 = fmaxf(ax1, bx1);
    float iy1 = fmaxf(ay1, by1);
    float ix2 = fminf(ax2, bx2);
    float iy2 = fminf(ay2, by2);
    float iw = fmaxf(ix2 - ix1, 0.0f);
    float ih = fmaxf(iy2 - iy1, 0.0f);
    float inter = iw * ih;
    float aa = (ax2 - ax1) * (ay2 - ay1);
    float ab = (bx2 - bx1) * (by2 - by1);
    return inter > 0.0f ? inter / (aa + ab - inter) : 0.0f;
}

__global__ __launch_bounds__(BLK) void yolo_stage1(const float* __restrict__ pred,
                                                   const float* __restrict__ lab,
                                                   float* __restrict__ partial) {
    __shared__ float4 sp4[NF4];
    __shared__ float4 sl4[NF4];
    __shared__ float swave[BLK / 64];

    const int tid = threadIdx.x;

    // ---- stage 2 batches -> LDS with aligned float4 loads (6-deep MLP) ----
    const size_t base_f = (size_t)blockIdx.x * (BPB * FPB);
    const float4* pg = (const float4*)(pred + base_f);   // 16B-aligned: 11760%16==0
    const float4* lg = (const float4*)(lab + base_f);

    float4 a0 = pg[tid];
    float4 c0 = lg[tid];
    float4 a1 = pg[tid + 256];
    float4 c1 = lg[tid + 256];
    float4 a2, c2;
    const bool t3 = tid < (NF4 - 512);   // tid < 223
    if (t3) { a2 = pg[tid + 512]; c2 = lg[tid + 512]; }

    sp4[tid] = a0;        sl4[tid] = c0;
    sp4[tid + 256] = a1;  sl4[tid + 256] = c1;
    if (t3) { sp4[tid + 512] = a2; sl4[tid + 512] = c2; }
    __syncthreads();

    const float* spf = (const float*)sp4;
    const float* slf = (const float*)sl4;

    // ---- per-cell loss (98 active threads; same math as verified rounds) ----
    float per_cell = 0.0f;
    if (tid < BPB * CELLS) {
        const int bl = tid / CELLS;          // 0 or 1
        const int cell = tid - bl * CELLS;
        const int mr = cell / GDIM;          // m (added to cx)
        const int nc = cell - mr * GDIM;     // n (added to cy)
        const float* p = spf + bl * FPB + cell;
        const float* l = slf + bl * FPB + cell;

        float pv[10], lv[10];
        #pragma unroll
        for (int c = 0; c < 10; ++c) pv[c] = p[c * CELLS];
        #pragma unroll
        for (int c = 0; c < 10; ++c) lv[c] = l[c * CELLS];

        float cls = 0.0f;
        #pragma unroll
        for (int c = 10; c < CH; ++c) {
            float d = p[c * CELLS] - l[c * CELLS];
            cls = fmaf(d, d, cls);
        }

        const float fm = (float)mr, fn = (float)nc;

        float gcx = (lv[0] + fm) / 7.0f;
        float gcy = (lv[1] + fn) / 7.0f;
        float gx1 = gcx - lv[2] * 0.5f, gy1 = gcy - lv[3] * 0.5f;
        float gx2 = gcx + lv[2] * 0.5f, gy2 = gcy + lv[3] * 0.5f;

        float c1x = (pv[0] + fm) / 7.0f;
        float c1y = (pv[1] + fn) / 7.0f;
        float b1x1 = c1x - pv[2] * 0.5f, b1y1 = c1y - pv[3] * 0.5f;
        float b1x2 = c1x + pv[2] * 0.5f, b1y2 = c1y + pv[3] * 0.5f;

        float c2x = (pv[5] + fm) / 7.0f;
        float c2y = (pv[6] + fn) / 7.0f;
        float b2x1 = c2x - pv[7] * 0.5f, b2y1 = c2y - pv[8] * 0.5f;
        float b2x2 = c2x + pv[7] * 0.5f, b2y2 = c2y + pv[8] * 0.5f;

        float iou1 = iou_fn(b1x1, b1y1, b1x2, b1y2, gx1, gy1, gx2, gy2);
        float iou2 = iou_fn(b2x1, b2y1, b2x2, b2y2, gx1, gy1, gx2, gy2);
        bool use1 = iou1 >= iou2;

        float d0 = pv[0] - lv[0], d1 = pv[1] - lv[1];
        float s2 = sqrtf(pv[2]) - sqrtf(lv[2]);
        float s3 = sqrtf(pv[3]) - sqrtf(lv[3]);
        float coor1 = d0 * d0 + d1 * d1 + s2 * s2 + s3 * s3;

        float d5 = pv[5] - lv[5], d6 = pv[6] - lv[6];
        float s7 = sqrtf(pv[7]) - sqrtf(lv[7]);
        float s8 = sqrtf(pv[8]) - sqrtf(lv[8]);
        float coor2 = d5 * d5 + d6 * d6 + s7 * s7 + s8 * s8;

        float coor = 5.0f * (use1 ? coor1 : coor2);

        float e1 = pv[4] - iou1; e1 *= e1;
        float e2 = pv[9] - iou2; e2 *= e2;
        float obj_conf   = use1 ? e1 : e2;
        float noobj_obj  = 0.5f * (use1 ? e2 : e1);
        float noobj_none = 0.5f * (pv[4] * pv[4] + pv[9] * pv[9]);

        bool obj = (lv[4] == 1.0f);
        per_cell = obj ? (coor + obj_conf + noobj_obj + cls) : noobj_none;
    }

    // ---- block reduction (deterministic) -> plain partial store ----
    float v = per_cell;
    #pragma unroll
    for (int off = 32; off > 0; off >>= 1) v += __shfl_down(v, off, 64);

    const int lane = tid & 63;
    const int wid = tid >> 6;
    if (lane == 0) swave[wid] = v;
    __syncthreads();
    if (tid == 0) {
        float s = 0.0f;
        #pragma unroll
        for (int w = 0; w < BLK / 64; ++w) s += swave[w];
        partial[blockIdx.x] = s;
    }
}

__global__ __launch_bounds__(BLK) void yolo_stage2(const float* __restrict__ partial,
                                                   int n, float inv_b,
                                                   float* __restrict__ out) {
    float v = 0.0f;
    for (int i = threadIdx.x; i < n; i += BLK) v += partial[i];
    #pragma unroll
    for (int off = 32; off > 0; off >>= 1) v += __shfl_down(v, off, 64);

    __shared__ float sdata[BLK / 64];
    int lane = threadIdx.x & 63;
    int wid  = threadIdx.x >> 6;
    if (lane == 0) sdata[wid] = v;
    __syncthreads();
    if (threadIdx.x == 0) {
        float s = 0.0f;
        #pragma unroll
        for (int w = 0; w < BLK / 64; ++w) s += sdata[w];
        out[0] = s * inv_b;
    }
}

extern "C" void kernel_launch(void* const* d_in, const int* in_sizes, int n_in,
                              void* d_out, int out_size, void* d_ws, size_t ws_size,
                              hipStream_t stream) {
    const float* pred = (const float*)d_in[0];
    const float* lab  = (const float*)d_in[1];
    int B = in_sizes[0] / FPB;          // 8192
    int nblocks = B / BPB;              // 4096 (8192 even)

    float* partial = (float*)d_ws;
    float* out = (float*)d_out;

    yolo_stage1<<<nblocks, BLK, 0, stream>>>(pred, lab, partial);
    yolo_stage2<<<1, BLK, 0, stream>>>(partial, nblocks, 1.0f / (float)B, out);
}